// Round 1
// baseline (768.434 us; speedup 1.0000x reference)
//
#include <hip/hip_runtime.h>

// Problem constants (match the JAX reference)
#define MAXVAL   5843
#define TOP_K    200
#define STEP_SZ  30
#define N_STEPS  189      // ceil((5843-200)/30)
#define BATCH    4

// One 64-lane wave per row. The row's surviving window is the 200 contiguous
// columns [start, start+200) with start = min(q,188)*30. Masked entries of the
// reference softmax are exp(-1e7 - max)/sum which underflows to exactly 0.0f
// in fp32, so writing literal 0.0f outside the window is exact.
//
// v2: the kernel writes the WHOLE row (zeros + window probabilities) itself.
// The previous version memset the full output first (and, per WRITE_SIZE =
// 2.185 GB = 4x the 546 MB output, out_size is a BYTE count so the memset was
// clearing 4x the buffer). Eliminating the memset removes a full extra pass
// over the output: floor is now write 546 MB + read ~19 MB in one dispatch.
__global__ __launch_bounds__(256) void window_softmax_fullrow(
        const float* __restrict__ X, float* __restrict__ Out) {
    const int gtid  = blockIdx.x * blockDim.x + threadIdx.x;
    const int wave  = gtid >> 6;          // global wave id == row id
    const int lane  = gtid & 63;
    const int nrows = BATCH * MAXVAL;
    if (wave >= nrows) return;

    const int q     = wave % MAXVAL;                       // query index within matrix
    const int start = (q < N_STEPS - 1 ? q : N_STEPS - 1) * STEP_SZ;
    const int wend  = start + TOP_K;                       // window end (exclusive)

    const size_t row_off = (size_t)wave * MAXVAL;
    const float* xrow = X + row_off;
    float*       orow = Out + row_off;

    // ---- Phase 1: softmax stats over the 200-wide window (200 = 3*64 + 8) ----
    float v[4];
    float m = -1e30f;
#pragma unroll
    for (int k = 0; k < 4; ++k) {
        const int idx = lane + 64 * k;
        v[k] = (idx < TOP_K) ? xrow[start + idx] : -1e30f;
        m = fmaxf(m, v[k]);
    }
#pragma unroll
    for (int off = 32; off > 0; off >>= 1)
        m = fmaxf(m, __shfl_xor(m, off, 64));

    float s = 0.0f;
#pragma unroll
    for (int k = 0; k < 4; ++k) {
        const int idx = lane + 64 * k;
        s += (idx < TOP_K) ? __expf(v[k] - m) : 0.0f;
    }
#pragma unroll
    for (int off = 32; off > 0; off >>= 1)
        s += __shfl_xor(s, off, 64);

    const float inv = 1.0f / s;   // wave-uniform after reduction

    // ---- Phase 2: write the full row. Zeros outside [start, wend). ----
    // Row base is only 4B-aligned (5843 % 4 == 3), so peel a scalar head to
    // reach 16B alignment, then float4 main body, then scalar tail.
    const int align  = (int)(row_off & 3);
    const int head_n = (4 - align) & 3;          // 0..3 scalar elems

    if (lane < head_n) {
        const int j = lane;
        float val = 0.0f;
        if (j >= start && j < wend) val = __expf(xrow[j] - m) * inv;
        orow[j] = val;
    }

    const int nquads = (MAXVAL - head_n) >> 2;   // full float4 stores
    float4* oq = (float4*)(orow + head_n);
    for (int qd = lane; qd < nquads; qd += 64) {
        const int j0 = head_n + qd * 4;
        float vv[4] = {0.0f, 0.0f, 0.0f, 0.0f};
        // Only quads overlapping the window need input reads (L1/L2 hit:
        // phase 1 just touched these 800 bytes).
        if (j0 + 3 >= start && j0 < wend) {
#pragma unroll
            for (int c = 0; c < 4; ++c) {
                const int j = j0 + c;
                if (j >= start && j < wend)
                    vv[c] = __expf(xrow[j] - m) * inv;
            }
        }
        oq[qd] = make_float4(vv[0], vv[1], vv[2], vv[3]);
    }

    const int tail_start = head_n + nquads * 4;
    const int tail_n     = MAXVAL - tail_start;  // 0..3 scalar elems
    if (lane < tail_n) {
        const int j = tail_start + lane;
        float val = 0.0f;
        if (j >= start && j < wend) val = __expf(xrow[j] - m) * inv;
        orow[j] = val;
    }
}

extern "C" void kernel_launch(void* const* d_in, const int* in_sizes, int n_in,
                              void* d_out, int out_size, void* d_ws, size_t ws_size,
                              hipStream_t stream) {
    const float* X = (const float*)d_in[0];
    float* out = (float*)d_out;

    // Single dispatch: each wave produces its entire output row, including
    // the zeros. No memset pass.
    const int nrows = BATCH * MAXVAL;            // 23372
    const int waves_per_block = 4;               // 256 threads
    const int blocks = (nrows + waves_per_block - 1) / waves_per_block;
    window_softmax_fullrow<<<blocks, 256, 0, stream>>>(X, out);
}

// Round 2
// 690.446 us; speedup vs baseline: 1.1130x; 1.1130x over previous
//
#include <hip/hip_runtime.h>

// Problem constants (match the JAX reference)
#define MAXVAL   5843
#define TOP_K    200
#define STEP_SZ  30
#define N_STEPS  189      // ceil((5843-200)/30)
#define BATCH    4

// One 64-lane wave per row. The row's surviving window is the 200 contiguous
// columns [start, start+200) with start = min(q,188)*30. Masked entries of the
// reference softmax are exp(-1e7 - max)/sum which underflows to exactly 0.0f
// in fp32, so zero-fill (done by hipMemsetAsync before this kernel) is exact.
//
// v3 note: out_size passed to kernel_launch is a BYTE count (evidence: the
// harness's own reset() poison fill writes out_size*4 = 2.185 GB — i.e. the
// allocation is out_size*sizeof(float) and out_size = 546 MB = exact logical
// output bytes). Round-0 memset of out_size*sizeof(float) therefore cleared
// 4x the needed bytes (346 us). Clearing exactly out_size bytes costs ~90 us
// at the measured 6.3 TB/s fill rate. The round-1 attempt to fold the zero
// writes into the softmax kernel ran at only ~1.5 TB/s (~370 us) — the HW
// fill path is strictly better, so we keep the memset + tiny-window split.
__global__ __launch_bounds__(256) void window_softmax_kernel(
        const float* __restrict__ X, float* __restrict__ Out) {
    const int gtid  = blockIdx.x * blockDim.x + threadIdx.x;
    const int wave  = gtid >> 6;          // global wave id == row id
    const int lane  = gtid & 63;
    const int nrows = BATCH * MAXVAL;
    if (wave >= nrows) return;

    const int q     = wave % MAXVAL;                       // query index within matrix
    const int start = (q < N_STEPS - 1 ? q : N_STEPS - 1) * STEP_SZ;

    const size_t row_off = (size_t)wave * MAXVAL + start;
    const float* xrow = X + row_off;

    // Load up to 4 window elements per lane (200 = 3*64 + 8)
    float v[4];
    float m = -1e30f;
#pragma unroll
    for (int k = 0; k < 4; ++k) {
        const int idx = lane + 64 * k;
        v[k] = (idx < TOP_K) ? xrow[idx] : -1e30f;
        m = fmaxf(m, v[k]);
    }
    // Wave-wide max (64 lanes)
#pragma unroll
    for (int off = 32; off > 0; off >>= 1)
        m = fmaxf(m, __shfl_xor(m, off, 64));

    // exp and wave-wide sum
    float s = 0.0f;
#pragma unroll
    for (int k = 0; k < 4; ++k) {
        const int idx = lane + 64 * k;
        v[k] = (idx < TOP_K) ? __expf(v[k] - m) : 0.0f;
        s += v[k];
    }
#pragma unroll
    for (int off = 32; off > 0; off >>= 1)
        s += __shfl_xor(s, off, 64);

    const float inv = 1.0f / s;

    float* orow = Out + row_off;
#pragma unroll
    for (int k = 0; k < 4; ++k) {
        const int idx = lane + 64 * k;
        if (idx < TOP_K) orow[idx] = v[k] * inv;
    }
}

extern "C" void kernel_launch(void* const* d_in, const int* in_sizes, int n_in,
                              void* d_out, int out_size, void* d_ws, size_t ws_size,
                              hipStream_t stream) {
    const float* X = (const float*)d_in[0];
    float* out = (float*)d_out;

    // 1) Zero exactly the logical output. out_size is a BYTE count (see note
    //    above) — do NOT multiply by sizeof(float).
    hipMemsetAsync(d_out, 0, (size_t)out_size, stream);

    // 2) Softmax over each row's 200-wide window; one wave per row.
    const int nrows = BATCH * MAXVAL;            // 23372
    const int waves_per_block = 4;               // 256 threads
    const int blocks = (nrows + waves_per_block - 1) / waves_per_block;
    window_softmax_kernel<<<blocks, 256, 0, stream>>>(X, out);
}